// Round 16
// baseline (124.461 us; speedup 1.0000x reference)
//
#include <hip/hip_runtime.h>

#define ALPHA 10.0f
#define BN_EPS 1e-5f
#define NVOX 32768   // 32*32*32
#define MDB 4096
#define CAP 128      // per-query candidate list capacity (E~53 @768-subset)

typedef __attribute__((ext_vector_type(8))) short short8;
typedef __attribute__((ext_vector_type(16))) float f32x16;

// ---------- 3-way bf16 split helpers ----------
__device__ __forceinline__ unsigned short bfr(float x) {
  unsigned u = __float_as_uint(x);
  return (unsigned short)((u + 0x7FFFu + ((u >> 16) & 1u)) >> 16);
}
__device__ __forceinline__ void split3(float x, unsigned short& h,
                                       unsigned short& m, unsigned short& l) {
  h = bfr(x);
  float fh = __uint_as_float((unsigned)h << 16);
  float x1 = x - fh;
  m = bfr(x1);
  float fm = __uint_as_float((unsigned)m << 16);
  l = bfr(x1 - fm);
}

// d2 tile: acc = (-2 db)·q  [hh+hm | mh+mm | lh+hl]  + dbdb + qq
__device__ __forceinline__ f32x16 d2_tile(short8 a1, short8 a2, short8 a3,
                                          short8 a4, short8 b1, short8 b3,
                                          short8 b4) {
  f32x16 acc = {};
  acc = __builtin_amdgcn_mfma_f32_32x32x16_bf16(a4, b4, acc, 0, 0, 0);
  acc = __builtin_amdgcn_mfma_f32_32x32x16_bf16(a3, b3, acc, 0, 0, 0);
  acc = __builtin_amdgcn_mfma_f32_32x32x16_bf16(a2, b1, acc, 0, 0, 0);
  acc = __builtin_amdgcn_mfma_f32_32x32x16_bf16(a1, b1, acc, 0, 0, 0);
  return acc;
}

__device__ __forceinline__ float fmin3(float a, float b, float c) {
  return fminf(fminf(a, b), c);
}

// Insert a PAIR of values into sorted-ascending d[0..9] (keep 10 smallest).
#define INSERT2(d, va, vb)                                              \
  do {                                                                  \
    float _lo = fminf((va), (vb)), _hi = fmaxf((va), (vb));             \
    _Pragma("unroll")                                                   \
    for (int _k = 9; _k >= 2; --_k)                                     \
      d[_k] = fmin3(d[_k], fmaxf(d[_k - 1], _lo), fmaxf(d[_k - 2], _hi)); \
    d[1] = fmin3(d[1], fmaxf(d[0], _lo), _hi);                          \
    d[0] = fminf(d[0], _lo);                                            \
  } while (0)

// ------- conv1 (blocks 0..127) + db prep (blocks 128..143), 256 thr -------
__global__ __launch_bounds__(256) void k_conv1p(
    const float* __restrict__ bg, const float* __restrict__ ed,
    const float* __restrict__ w1, const float* __restrict__ b1,
    const float* __restrict__ g1, const float* __restrict__ be1,
    const float* __restrict__ m1, const float* __restrict__ v1,
    float* __restrict__ A, const float* __restrict__ db,
    unsigned short* __restrict__ DBH, unsigned short* __restrict__ DBM,
    unsigned short* __restrict__ DBL, unsigned short* __restrict__ DB4) {
  int t = threadIdx.x;
  if (blockIdx.x >= 128) {  // ---- prep path ----
    int j = (blockIdx.x - 128) * 256 + t;
    float4 x0 = ((const float4*)(db + (size_t)j * 8))[0];
    float4 x1 = ((const float4*)(db + (size_t)j * 8))[1];
    float x[8] = {x0.x, x0.y, x0.z, x0.w, x1.x, x1.y, x1.z, x1.w};
    float ss = x[0] * x[0];
#pragma unroll
    for (int i = 1; i < 8; ++i) ss = fmaf(x[i], x[i], ss);
    short8 sh = {}, sm = {}, sl = {};
#pragma unroll
    for (int i = 0; i < 8; ++i) {
      unsigned short h, m, l;
      split3(-2.f * x[i], h, m, l);
      sh[i] = (short)h; sm[i] = (short)m; sl[i] = (short)l;
    }
    unsigned short dh, dm, dl;
    split3(ss, dh, dm, dl);
    short8 s4 = {};
    s4[0] = (short)dh; s4[1] = (short)dm; s4[2] = (short)dl;
    s4[3] = (short)0x3F80; s4[4] = (short)0x3F80; s4[5] = (short)0x3F80;
    *(short8*)(DBH + (size_t)j * 8) = sh;
    *(short8*)(DBM + (size_t)j * 8) = sm;
    *(short8*)(DBL + (size_t)j * 8) = sl;
    *(short8*)(DB4 + (size_t)j * 8) = s4;
    return;
  }
  // ---- conv1 path ----
  __shared__ float wT[54 * 16];
  __shared__ float sc[16], shs[16];
  for (int i = t; i < 864; i += 256) {
    int o = i & 15, r = i >> 4;
    wT[i] = w1[o * 54 + r];
  }
  if (t < 16) {
    float s = g1[t] * rsqrtf(v1[t] + BN_EPS);
    sc[t] = s;
    shs[t] = (b1[t] - m1[t]) * s + be1[t];
  }
  __syncthreads();
  int v = blockIdx.x * 256 + t;
  int x = v & 31, y = (v >> 5) & 31, z = v >> 10;
  float acc[16];
#pragma unroll
  for (int o = 0; o < 16; ++o) acc[o] = 0.f;
#pragma unroll 1
  for (int k = 0; k < 27; ++k) {
    int dz = k / 9 - 1, dy = (k / 3) % 3 - 1, dx = k % 3 - 1;
    int zz = z + dz, yy = y + dy, xx = x + dx;
    bool inb = (unsigned)zz < 32u && (unsigned)yy < 32u && (unsigned)xx < 32u;
    int vv = zz * 1024 + yy * 32 + xx;
#pragma unroll
    for (int c = 0; c < 2; ++c) {
      const float* in = c ? ed : bg;
      float val = inb ? in[vv] : 0.f;
      const float4* wp = (const float4*)&wT[(c * 27 + k) * 16];
      float4 wa = wp[0], wb = wp[1], wc = wp[2], wd = wp[3];
      acc[0] = fmaf(val, wa.x, acc[0]);  acc[1] = fmaf(val, wa.y, acc[1]);
      acc[2] = fmaf(val, wa.z, acc[2]);  acc[3] = fmaf(val, wa.w, acc[3]);
      acc[4] = fmaf(val, wb.x, acc[4]);  acc[5] = fmaf(val, wb.y, acc[5]);
      acc[6] = fmaf(val, wb.z, acc[6]);  acc[7] = fmaf(val, wb.w, acc[7]);
      acc[8] = fmaf(val, wc.x, acc[8]);  acc[9] = fmaf(val, wc.y, acc[9]);
      acc[10] = fmaf(val, wc.z, acc[10]); acc[11] = fmaf(val, wc.w, acc[11]);
      acc[12] = fmaf(val, wd.x, acc[12]); acc[13] = fmaf(val, wd.y, acc[13]);
      acc[14] = fmaf(val, wd.z, acc[14]); acc[15] = fmaf(val, wd.w, acc[15]);
    }
  }
#pragma unroll
  for (int o = 0; o < 16; ++o) {
    float y2 = fmaf(acc[o], sc[o], shs[o]);
    A[o * NVOX + v] = y2 > 0.f ? y2 : 0.f;
  }
}

// ===== fused conv2 + conv3 + kNN: block = 32 queries (one x-row) =====
// prologue: stage A-halo [16][3][3][34] -> conv2 (bit-identical order to the
//           old standalone kernel) -> C2 LDS -> per-lane conv3/normalize/split
// A: exact top-10 of a 768-row subset (3 tiles/wave) -> bound T0
// B: single full scan; collect (d2, row-index) with d2 <= T0 into LDS lists
// C: (i) t<32: exact top-10 -> T, den; (ii) all threads: partial num
__global__ __launch_bounds__(512) void k_knn_fused(
    const float* __restrict__ A, const float* __restrict__ w2,
    const float* __restrict__ b2, const float* __restrict__ g2,
    const float* __restrict__ be2, const float* __restrict__ m2,
    const float* __restrict__ v2, const float* __restrict__ w3,
    const float* __restrict__ b3c,
    const unsigned short* __restrict__ DBH, const unsigned short* __restrict__ DBM,
    const unsigned short* __restrict__ DBL, const unsigned short* __restrict__ DB4,
    const float* __restrict__ labels, float* __restrict__ out) {
  __shared__ float smem[2 * 32 * (CAP + 1)];  // lists; prologue+stageA alias
  __shared__ float T0L[32];
  __shared__ int cnt[32];
  __shared__ float pn[32][16];
  __shared__ float wTl[256];  // [ci][o] transposed conv3 weights
  __shared__ float bLl[8];
  float (*listd)[CAP + 1] = (float (*)[CAP + 1])smem;
  int (*listi)[CAP + 1] = (int (*)[CAP + 1])(smem + 32 * (CAP + 1));
  float (*lds_top)[10][32] = (float (*)[10][32])smem;  // stage A (dead later)
  float* AH = smem;             // [16ci][3z][3y][34x] = 4896 floats
  float* C2 = smem + 4896;      // [32oc][32x] = 1024 floats

  int t = threadIdx.x, w = t >> 6, l = t & 63;
  int lo32 = l & 31, hi = l >> 5;
  if (t < 32) cnt[t] = 0;
  if (t < 256) wTl[t] = w3[(t & 7) * 32 + (t >> 3)];  // wTl[ci*8+o]
  if (t >= 504) bLl[t - 504] = b3c[t - 504];

  int y0 = blockIdx.x & 31, z0 = blockIdx.x >> 5;

  // ---- prologue 1: stage A-halo (zero-padded) into LDS ----
  for (int i = t; i < 4896; i += 512) {
    int xi = i % 34;
    int rest = i / 34;
    int yi = rest % 3;
    rest /= 3;
    int zi = rest % 3;
    int ci = rest / 3;
    int xx = xi - 1, yy = y0 + yi - 1, zz = z0 + zi - 1;
    bool inb = (unsigned)xx < 32u && (unsigned)yy < 32u && (unsigned)zz < 32u;
    AH[i] = inb ? A[(size_t)ci * NVOX + zz * 1024 + yy * 32 + xx] : 0.f;
  }
  __syncthreads();

  // ---- prologue 2: conv2 (+BN+ReLU); thread -> (x=t&31, oc={t>>5, +16}) ----
  {
    int x = t & 31;
    int oc0 = t >> 5, oc1 = oc0 + 16;
    float acc0 = 0.f, acc1 = 0.f;
#pragma unroll 1
    for (int k = 0; k < 27; ++k) {
      int kz = k / 9, ky = (k / 3) % 3, kx = k % 3;
      int base = kz * 102 + ky * 34 + x + kx;  // within one ci slab (306)
#pragma unroll
      for (int ci = 0; ci < 16; ++ci) {
        float val = AH[ci * 306 + base];
        acc0 = fmaf(val, w2[(size_t)oc0 * 432 + ci * 27 + k], acc0);
        acc1 = fmaf(val, w2[(size_t)oc1 * 432 + ci * 27 + k], acc1);
      }
    }
    float s0 = g2[oc0] * rsqrtf(v2[oc0] + BN_EPS);
    float h0 = (b2[oc0] - m2[oc0]) * s0 + be2[oc0];
    float s1 = g2[oc1] * rsqrtf(v2[oc1] + BN_EPS);
    float h1 = (b2[oc1] - m2[oc1]) * s1 + be2[oc1];
    float r0 = fmaf(acc0, s0, h0);
    float r1 = fmaf(acc1, s1, h1);
    __syncthreads();  // AH reads done before C2 (aliased region) writes? C2
    // is at smem+4896 (disjoint from AH) -- barrier here is for AH-read
    // completion before stage A later; keep for write ordering safety.
    C2[oc0 * 32 + x] = r0 > 0.f ? r0 : 0.f;
    C2[oc1 * 32 + x] = r1 > 0.f ? r1 : 0.f;
  }
  __syncthreads();

  // ---- prologue 3: per-lane conv3 + normalize + split (registers) ----
  short8 zz8 = {};
  short8 b1f, b3f, b4f;
  {
    float lat[8];
#pragma unroll
    for (int o = 0; o < 8; ++o) lat[o] = bLl[o];
#pragma unroll 4
    for (int ci = 0; ci < 32; ++ci) {
      float val = C2[ci * 32 + lo32];  // 32 distinct consecutive -> no conflict
      const float4* wp = (const float4*)&wTl[ci * 8];
      float4 wa = wp[0], wb = wp[1];
      lat[0] = fmaf(val, wa.x, lat[0]); lat[1] = fmaf(val, wa.y, lat[1]);
      lat[2] = fmaf(val, wa.z, lat[2]); lat[3] = fmaf(val, wa.w, lat[3]);
      lat[4] = fmaf(val, wb.x, lat[4]); lat[5] = fmaf(val, wb.y, lat[5]);
      lat[6] = fmaf(val, wb.z, lat[6]); lat[7] = fmaf(val, wb.w, lat[7]);
    }
    float n2 = 0.f;
#pragma unroll
    for (int o = 0; o < 8; ++o) n2 = fmaf(lat[o], lat[o], n2);
    float inv = 1.f / fmaxf(sqrtf(n2), 1e-12f);
    float qv[8];
#pragma unroll
    for (int o = 0; o < 8; ++o) qv[o] = lat[o] * inv;
    float qq2 = qv[0] * qv[0];
#pragma unroll
    for (int o = 1; o < 8; ++o) qq2 = fmaf(qv[o], qv[o], qq2);
    short8 sh = {}, sm = {}, sl = {};
#pragma unroll
    for (int o = 0; o < 8; ++o) {
      unsigned short h, m, lo;
      split3(qv[o], h, m, lo);
      sh[o] = (short)h; sm[o] = (short)m; sl[o] = (short)lo;
    }
    unsigned short qh, qm, ql;
    split3(qq2, qh, qm, ql);
    short8 s4 = {};
    s4[0] = (short)0x3F80; s4[1] = (short)0x3F80; s4[2] = (short)0x3F80;
    s4[3] = (short)qh; s4[4] = (short)qm; s4[5] = (short)ql;
    b1f = hi ? sm : sh;
    b3f = hi ? sl : sh;
    b4f = hi ? zz8 : s4;
  }
  __syncthreads();  // C2 reads done; smem free for stage A
  int r0 = w * 512;

  // ---- stage A: exact top-10 over this wave's first 3 tiles ----
  float d[10];
#pragma unroll
  for (int k = 0; k < 10; ++k) d[k] = 3.4e38f;
#pragma unroll 1
  for (int tt = 0; tt < 3; ++tt) {
    int r = r0 + tt * 32 + lo32;
    short8 a1 = *(const short8*)(DBH + (size_t)r * 8);
    short8 a2 = *(const short8*)(DBM + (size_t)r * 8);
    short8 a3 = *(const short8*)((hi ? DBH : DBL) + (size_t)r * 8);
    short8 a4 = *(const short8*)(DB4 + (size_t)r * 8);
    f32x16 acc = d2_tile(a1, a2, a3, a4, b1f, b3f, b4f);
#pragma unroll
    for (int p = 0; p < 8; ++p) INSERT2(d, acc[2 * p], acc[2 * p + 1]);
  }
  {  // merge the two lane-halves (complementary row subsets, same query)
    float e[10];
#pragma unroll
    for (int k = 0; k < 10; ++k) e[k] = __shfl_xor(d[k], 32);
#pragma unroll
    for (int k = 0; k < 10; k += 2) INSERT2(d, e[k], e[k + 1]);
  }
  if (l < 32) {
#pragma unroll
    for (int k = 0; k < 10; ++k) lds_top[w][k][lo32] = d[k];
  }
  __syncthreads();
  if (t < 32) {  // exact 10th-smallest of the 768-row subset, per query
    float m[10];
#pragma unroll
    for (int k = 0; k < 10; ++k) m[k] = 3.4e38f;
#pragma unroll 1
    for (int w2i = 0; w2i < 8; ++w2i) {
#pragma unroll
      for (int k2 = 0; k2 < 10; k2 += 2)
        INSERT2(m, lds_top[w2i][k2][t], lds_top[w2i][k2 + 1][t]);
    }
    T0L[t] = m[9];
  }
  __syncthreads();
  float T0q = T0L[lo32];

  // ---- stage B: single full scan; collect (d2, row idx) with d2 <= T0 ----
#pragma unroll 1
  for (int tt = 0; tt < 16; ++tt) {
    int r = r0 + tt * 32 + lo32;
    short8 a1 = *(const short8*)(DBH + (size_t)r * 8);
    short8 a2 = *(const short8*)(DBM + (size_t)r * 8);
    short8 a3 = *(const short8*)((hi ? DBH : DBL) + (size_t)r * 8);
    short8 a4 = *(const short8*)(DB4 + (size_t)r * 8);
    f32x16 acc = d2_tile(a1, a2, a3, a4, b1f, b3f, b4f);
    int rb = r0 + tt * 32 + 4 * hi;
#pragma unroll
    for (int i = 0; i < 16; ++i) {
      float d2v = acc[i];
      if (d2v <= T0q) {  // rare per lane (~1.3%)
        int slot = atomicAdd(&cnt[lo32], 1);
        if (slot < CAP) {
          listd[lo32][slot] = d2v;
          listi[lo32][slot] = rb + (i & 3) + 8 * (i >> 2);
        }
      }
    }
  }
  __syncthreads();

  // ---- stage C(i): t<32 exact top-10 -> T, den ----
  float den = 0.f;
  if (t < 32) {
    int n = min(cnt[t], CAP);
    float dd[10];
#pragma unroll
    for (int k = 0; k < 10; ++k) dd[k] = 3.4e38f;
    int j = 0;
#pragma unroll 1
    for (; j + 1 < n; j += 2) INSERT2(dd, listd[t][j], listd[t][j + 1]);
    if (j < n) INSERT2(dd, listd[t][j], 3.4e38f);
    const float C2c = -14.4269504088896340736f;
#pragma unroll
    for (int k = 0; k < 10; ++k) den += exp2f(dd[k] * C2c);
    T0L[t] = dd[9];  // reuse (T0 dead): exact 10th-smallest = T
  }
  __syncthreads();

  // ---- stage C(ii): all threads, partial num with global label gather ----
  {
    const float C2c = -14.4269504088896340736f;
    int qc = t >> 4, s0 = t & 15;
    int n = min(cnt[qc], CAP);
    float Tq = T0L[qc];
    float nump = 0.f;
    for (int s = s0; s < n; s += 16) {
      float v = listd[qc][s];
      if (v <= Tq) nump = fmaf(exp2f(v * C2c), labels[listi[qc][s]], nump);
    }
    pn[qc][s0] = nump;
  }
  __syncthreads();
  if (t < 32) {
    float num = 0.f;
#pragma unroll
    for (int g = 0; g < 16; ++g) num += pn[t][g];
    out[blockIdx.x * 32 + t] = num / (den + 1e-8f);
  }
}

extern "C" void kernel_launch(void* const* d_in, const int* in_sizes, int n_in,
                              void* d_out, int out_size, void* d_ws, size_t ws_size,
                              hipStream_t stream) {
  const float* bg = (const float*)d_in[0];
  const float* ed = (const float*)d_in[1];
  const float* w1 = (const float*)d_in[3];
  const float* b1 = (const float*)d_in[4];
  const float* g1 = (const float*)d_in[5];
  const float* be1 = (const float*)d_in[6];
  const float* m1 = (const float*)d_in[7];
  const float* v1 = (const float*)d_in[8];
  const float* w2 = (const float*)d_in[9];
  const float* b2 = (const float*)d_in[10];
  const float* g2 = (const float*)d_in[11];
  const float* be2 = (const float*)d_in[12];
  const float* m2 = (const float*)d_in[13];
  const float* v2 = (const float*)d_in[14];
  const float* w3 = (const float*)d_in[15];
  const float* b3 = (const float*)d_in[16];
  const float* db = (const float*)d_in[17];
  const float* labels = (const float*)d_in[18];
  float* out = (float*)d_out;

  char* ws = (char*)d_ws;
  // layout:
  //  [0,2M)     A (conv1 out; live through knn prologue)
  //  [6M,6.25M) DBH/DBM/DBL/DB4 (4x64KB)
  const size_t MB = 1024 * 1024;
  float* A = (float*)(ws + 0);
  unsigned short* DBH = (unsigned short*)(ws + 6 * MB);
  unsigned short* DBM = DBH + (size_t)MDB * 8;
  unsigned short* DBL = DBM + (size_t)MDB * 8;
  unsigned short* DB4 = DBL + (size_t)MDB * 8;

  k_conv1p<<<144, 256, 0, stream>>>(bg, ed, w1, b1, g1, be1, m1, v1, A, db,
                                    DBH, DBM, DBL, DB4);
  k_knn_fused<<<NVOX / 32, 512, 0, stream>>>(A, w2, b2, g2, be2, m2, v2, w3,
                                             b3, DBH, DBM, DBL, DB4, labels,
                                             out);
}

// Round 17
// 107.424 us; speedup vs baseline: 1.1586x; 1.1586x over previous
//
#include <hip/hip_runtime.h>

#define ALPHA 10.0f
#define BN_EPS 1e-5f
#define NVOX 32768   // 32*32*32
#define MDB 4096
#define CAP 128      // per-query candidate list capacity (E~53 @768-subset)

typedef __attribute__((ext_vector_type(8))) short short8;
typedef __attribute__((ext_vector_type(16))) float f32x16;

// ---------- 3-way bf16 split helpers ----------
__device__ __forceinline__ unsigned short bfr(float x) {
  unsigned u = __float_as_uint(x);
  return (unsigned short)((u + 0x7FFFu + ((u >> 16) & 1u)) >> 16);
}
__device__ __forceinline__ void split3(float x, unsigned short& h,
                                       unsigned short& m, unsigned short& l) {
  h = bfr(x);
  float fh = __uint_as_float((unsigned)h << 16);
  float x1 = x - fh;
  m = bfr(x1);
  float fm = __uint_as_float((unsigned)m << 16);
  l = bfr(x1 - fm);
}

// d2 tile: acc = (-2 db)·q  [hh+hm | mh+mm | lh+hl]  + dbdb + qq
// One shared sequence -> bit-identical d2 everywhere it is computed.
__device__ __forceinline__ f32x16 d2_tile(short8 a1, short8 a2, short8 a3,
                                          short8 a4, short8 b1, short8 b3,
                                          short8 b4) {
  f32x16 acc = {};
  acc = __builtin_amdgcn_mfma_f32_32x32x16_bf16(a4, b4, acc, 0, 0, 0);
  acc = __builtin_amdgcn_mfma_f32_32x32x16_bf16(a3, b3, acc, 0, 0, 0);
  acc = __builtin_amdgcn_mfma_f32_32x32x16_bf16(a2, b1, acc, 0, 0, 0);
  acc = __builtin_amdgcn_mfma_f32_32x32x16_bf16(a1, b1, acc, 0, 0, 0);
  return acc;
}

__device__ __forceinline__ float fmin3(float a, float b, float c) {
  return fminf(fminf(a, b), c);
}

// Insert a PAIR of values into sorted-ascending d[0..9] (keep 10 smallest).
#define INSERT2(d, va, vb)                                              \
  do {                                                                  \
    float _lo = fminf((va), (vb)), _hi = fmaxf((va), (vb));             \
    _Pragma("unroll")                                                   \
    for (int _k = 9; _k >= 2; --_k)                                     \
      d[_k] = fmin3(d[_k], fmaxf(d[_k - 1], _lo), fmaxf(d[_k - 2], _hi)); \
    d[1] = fmin3(d[1], fmaxf(d[0], _lo), _hi);                          \
    d[0] = fminf(d[0], _lo);                                            \
  } while (0)

// ------- conv1 (blocks 0..127) + db prep (blocks 128..143), 256 thr -------
__global__ __launch_bounds__(256) void k_conv1p(
    const float* __restrict__ bg, const float* __restrict__ ed,
    const float* __restrict__ w1, const float* __restrict__ b1,
    const float* __restrict__ g1, const float* __restrict__ be1,
    const float* __restrict__ m1, const float* __restrict__ v1,
    float* __restrict__ A, const float* __restrict__ db,
    unsigned short* __restrict__ DBH, unsigned short* __restrict__ DBM,
    unsigned short* __restrict__ DBL, unsigned short* __restrict__ DB4) {
  int t = threadIdx.x;
  if (blockIdx.x >= 128) {  // ---- prep path ----
    int j = (blockIdx.x - 128) * 256 + t;
    float4 x0 = ((const float4*)(db + (size_t)j * 8))[0];
    float4 x1 = ((const float4*)(db + (size_t)j * 8))[1];
    float x[8] = {x0.x, x0.y, x0.z, x0.w, x1.x, x1.y, x1.z, x1.w};
    float ss = x[0] * x[0];
#pragma unroll
    for (int i = 1; i < 8; ++i) ss = fmaf(x[i], x[i], ss);
    short8 sh = {}, sm = {}, sl = {};
#pragma unroll
    for (int i = 0; i < 8; ++i) {
      unsigned short h, m, l;
      split3(-2.f * x[i], h, m, l);
      sh[i] = (short)h; sm[i] = (short)m; sl[i] = (short)l;
    }
    unsigned short dh, dm, dl;
    split3(ss, dh, dm, dl);
    short8 s4 = {};
    s4[0] = (short)dh; s4[1] = (short)dm; s4[2] = (short)dl;
    s4[3] = (short)0x3F80; s4[4] = (short)0x3F80; s4[5] = (short)0x3F80;
    *(short8*)(DBH + (size_t)j * 8) = sh;
    *(short8*)(DBM + (size_t)j * 8) = sm;
    *(short8*)(DBL + (size_t)j * 8) = sl;
    *(short8*)(DB4 + (size_t)j * 8) = s4;
    return;
  }
  // ---- conv1 path ----
  __shared__ float wT[54 * 16];
  __shared__ float sc[16], shs[16];
  for (int i = t; i < 864; i += 256) {
    int o = i & 15, r = i >> 4;
    wT[i] = w1[o * 54 + r];
  }
  if (t < 16) {
    float s = g1[t] * rsqrtf(v1[t] + BN_EPS);
    sc[t] = s;
    shs[t] = (b1[t] - m1[t]) * s + be1[t];
  }
  __syncthreads();
  int v = blockIdx.x * 256 + t;
  int x = v & 31, y = (v >> 5) & 31, z = v >> 10;
  float acc[16];
#pragma unroll
  for (int o = 0; o < 16; ++o) acc[o] = 0.f;
#pragma unroll 1
  for (int k = 0; k < 27; ++k) {
    int dz = k / 9 - 1, dy = (k / 3) % 3 - 1, dx = k % 3 - 1;
    int zz = z + dz, yy = y + dy, xx = x + dx;
    bool inb = (unsigned)zz < 32u && (unsigned)yy < 32u && (unsigned)xx < 32u;
    int vv = zz * 1024 + yy * 32 + xx;
#pragma unroll
    for (int c = 0; c < 2; ++c) {
      const float* in = c ? ed : bg;
      float val = inb ? in[vv] : 0.f;
      const float4* wp = (const float4*)&wT[(c * 27 + k) * 16];
      float4 wa = wp[0], wb = wp[1], wc = wp[2], wd = wp[3];
      acc[0] = fmaf(val, wa.x, acc[0]);  acc[1] = fmaf(val, wa.y, acc[1]);
      acc[2] = fmaf(val, wa.z, acc[2]);  acc[3] = fmaf(val, wa.w, acc[3]);
      acc[4] = fmaf(val, wb.x, acc[4]);  acc[5] = fmaf(val, wb.y, acc[5]);
      acc[6] = fmaf(val, wb.z, acc[6]);  acc[7] = fmaf(val, wb.w, acc[7]);
      acc[8] = fmaf(val, wc.x, acc[8]);  acc[9] = fmaf(val, wc.y, acc[9]);
      acc[10] = fmaf(val, wc.z, acc[10]); acc[11] = fmaf(val, wc.w, acc[11]);
      acc[12] = fmaf(val, wd.x, acc[12]); acc[13] = fmaf(val, wd.y, acc[13]);
      acc[14] = fmaf(val, wd.z, acc[14]); acc[15] = fmaf(val, wd.w, acc[15]);
    }
  }
#pragma unroll
  for (int o = 0; o < 16; ++o) {
    float y2 = fmaf(acc[o], sc[o], shs[o]);
    A[o * NVOX + v] = y2 > 0.f ? y2 : 0.f;
  }
}

// -------- conv2: 16->32, k3, pad1, +BN+ReLU; 8 out-ch per block-group -----
__global__ __launch_bounds__(256) void k_conv2(
    const float* __restrict__ A, const float* __restrict__ w2,
    const float* __restrict__ b2, const float* __restrict__ g2,
    const float* __restrict__ be2, const float* __restrict__ m2,
    const float* __restrict__ v2, float* __restrict__ B) {
  __shared__ float wT[432 * 8];
  __shared__ float sc[8], shs[8];
  int t = threadIdx.x;
  int og = blockIdx.x >> 7;
  int vb = blockIdx.x & 127;
  for (int i = t; i < 3456; i += 256) {
    int o = i & 7, r = i >> 3;
    wT[i] = w2[(og * 8 + o) * 432 + r];
  }
  if (t < 8) {
    int o = og * 8 + t;
    float s = g2[o] * rsqrtf(v2[o] + BN_EPS);
    sc[t] = s;
    shs[t] = (b2[o] - m2[o]) * s + be2[o];
  }
  __syncthreads();
  int v = vb * 256 + t;
  int x = v & 31, y = (v >> 5) & 31, z = v >> 10;
  float acc[8];
#pragma unroll
  for (int o = 0; o < 8; ++o) acc[o] = 0.f;
#pragma unroll 1
  for (int k = 0; k < 27; ++k) {
    int dz = k / 9 - 1, dy = (k / 3) % 3 - 1, dx = k % 3 - 1;
    int zz = z + dz, yy = y + dy, xx = x + dx;
    bool inb = (unsigned)zz < 32u && (unsigned)yy < 32u && (unsigned)xx < 32u;
    int vv = zz * 1024 + yy * 32 + xx;
#pragma unroll
    for (int ci = 0; ci < 16; ++ci) {
      float val = inb ? A[ci * NVOX + vv] : 0.f;
      const float4* wp = (const float4*)&wT[(ci * 27 + k) * 8];
      float4 wa = wp[0], wb = wp[1];
      acc[0] = fmaf(val, wa.x, acc[0]); acc[1] = fmaf(val, wa.y, acc[1]);
      acc[2] = fmaf(val, wa.z, acc[2]); acc[3] = fmaf(val, wa.w, acc[3]);
      acc[4] = fmaf(val, wb.x, acc[4]); acc[5] = fmaf(val, wb.y, acc[5]);
      acc[6] = fmaf(val, wb.z, acc[6]); acc[7] = fmaf(val, wb.w, acc[7]);
    }
  }
#pragma unroll
  for (int o = 0; o < 8; ++o) {
    float y2 = fmaf(acc[o], sc[o], shs[o]);
    B[(og * 8 + o) * NVOX + v] = y2 > 0.f ? y2 : 0.f;
  }
}

// ===== fused conv3 + kNN: block = 32 queries; 8 waves x 512 rows each =====
// prologue: PER-LANE redundant conv3 (registers only, zero LDS conflicts)
// A: exact top-10 of a 768-row subset (3 tiles/wave) -> bound T0
// B: single full scan; collect (d2, row-index) with d2 <= T0 into LDS lists
// C: (i) t<32: exact top-10 -> T, den; (ii) all threads: partial num
__global__ __launch_bounds__(512) void k_knn_fused(
    const float* __restrict__ B, const float* __restrict__ w3,
    const float* __restrict__ b3c,
    const unsigned short* __restrict__ DBH, const unsigned short* __restrict__ DBM,
    const unsigned short* __restrict__ DBL, const unsigned short* __restrict__ DB4,
    const float* __restrict__ labels, float* __restrict__ out) {
  __shared__ float smem[2 * 32 * (CAP + 1)];  // lists; stage-A top10 aliased
  __shared__ float T0L[32];
  __shared__ int cnt[32];
  __shared__ float pn[32][16];
  __shared__ float wTl[256];  // [ci][o] transposed conv3 weights
  __shared__ float bLl[8];
  float (*listd)[CAP + 1] = (float (*)[CAP + 1])smem;
  int (*listi)[CAP + 1] = (int (*)[CAP + 1])(smem + 32 * (CAP + 1));
  float (*lds_top)[10][32] = (float (*)[10][32])smem;  // stage A (dead later)

  int t = threadIdx.x, w = t >> 6, l = t & 63;
  int lo32 = l & 31, hi = l >> 5;
  if (t < 32) cnt[t] = 0;
  if (t < 256) wTl[t] = w3[(t & 7) * 32 + (t >> 3)];  // wTl[ci*8+o]
  if (t >= 504) bLl[t - 504] = b3c[t - 504];
  __syncthreads();

  // ---- prologue: per-lane conv3 + normalize + split (registers only) ----
  short8 zz = {};
  short8 b1, b3, b4;
  {
    int v = blockIdx.x * 32 + lo32;
    float lat[8];
#pragma unroll
    for (int o = 0; o < 8; ++o) lat[o] = bLl[o];
#pragma unroll 4
    for (int ci = 0; ci < 32; ++ci) {
      float val = B[(size_t)ci * NVOX + v];  // coalesced per half-wave
      const float4* wp = (const float4*)&wTl[ci * 8];  // broadcast read
      float4 wa = wp[0], wb = wp[1];
      lat[0] = fmaf(val, wa.x, lat[0]); lat[1] = fmaf(val, wa.y, lat[1]);
      lat[2] = fmaf(val, wa.z, lat[2]); lat[3] = fmaf(val, wa.w, lat[3]);
      lat[4] = fmaf(val, wb.x, lat[4]); lat[5] = fmaf(val, wb.y, lat[5]);
      lat[6] = fmaf(val, wb.z, lat[6]); lat[7] = fmaf(val, wb.w, lat[7]);
    }
    float n2 = 0.f;
#pragma unroll
    for (int o = 0; o < 8; ++o) n2 = fmaf(lat[o], lat[o], n2);
    float inv = 1.f / fmaxf(sqrtf(n2), 1e-12f);
    float qv[8];
#pragma unroll
    for (int o = 0; o < 8; ++o) qv[o] = lat[o] * inv;
    float qq2 = qv[0] * qv[0];
#pragma unroll
    for (int o = 1; o < 8; ++o) qq2 = fmaf(qv[o], qv[o], qq2);
    short8 sh = {}, sm = {}, sl = {};
#pragma unroll
    for (int o = 0; o < 8; ++o) {
      unsigned short h, m, lo;
      split3(qv[o], h, m, lo);
      sh[o] = (short)h; sm[o] = (short)m; sl[o] = (short)lo;
    }
    unsigned short qh, qm, ql;
    split3(qq2, qh, qm, ql);
    short8 s4 = {};
    s4[0] = (short)0x3F80; s4[1] = (short)0x3F80; s4[2] = (short)0x3F80;
    s4[3] = (short)qh; s4[4] = (short)qm; s4[5] = (short)ql;
    b1 = hi ? sm : sh;
    b3 = hi ? sl : sh;
    b4 = hi ? zz : s4;
  }
  int r0 = w * 512;

  // ---- stage A: exact top-10 over this wave's first 3 tiles ----
  float d[10];
#pragma unroll
  for (int k = 0; k < 10; ++k) d[k] = 3.4e38f;
#pragma unroll 1
  for (int tt = 0; tt < 3; ++tt) {
    int r = r0 + tt * 32 + lo32;
    short8 a1 = *(const short8*)(DBH + (size_t)r * 8);
    short8 a2 = *(const short8*)(DBM + (size_t)r * 8);
    short8 a3 = *(const short8*)((hi ? DBH : DBL) + (size_t)r * 8);
    short8 a4 = *(const short8*)(DB4 + (size_t)r * 8);
    f32x16 acc = d2_tile(a1, a2, a3, a4, b1, b3, b4);
#pragma unroll
    for (int p = 0; p < 8; ++p) INSERT2(d, acc[2 * p], acc[2 * p + 1]);
  }
  {  // merge the two lane-halves (complementary row subsets, same query)
    float e[10];
#pragma unroll
    for (int k = 0; k < 10; ++k) e[k] = __shfl_xor(d[k], 32);
#pragma unroll
    for (int k = 0; k < 10; k += 2) INSERT2(d, e[k], e[k + 1]);
  }
  if (l < 32) {
#pragma unroll
    for (int k = 0; k < 10; ++k) lds_top[w][k][lo32] = d[k];
  }
  __syncthreads();
  if (t < 32) {  // exact 10th-smallest of the 768-row subset, per query
    float m[10];
#pragma unroll
    for (int k = 0; k < 10; ++k) m[k] = 3.4e38f;
#pragma unroll 1
    for (int w2 = 0; w2 < 8; ++w2) {
#pragma unroll
      for (int k2 = 0; k2 < 10; k2 += 2)
        INSERT2(m, lds_top[w2][k2][t], lds_top[w2][k2 + 1][t]);
    }
    T0L[t] = m[9];
  }
  __syncthreads();
  float T0q = T0L[lo32];

  // ---- stage B: single full scan; collect (d2, row idx) with d2 <= T0 ----
#pragma unroll 1
  for (int tt = 0; tt < 16; ++tt) {
    int r = r0 + tt * 32 + lo32;
    short8 a1 = *(const short8*)(DBH + (size_t)r * 8);
    short8 a2 = *(const short8*)(DBM + (size_t)r * 8);
    short8 a3 = *(const short8*)((hi ? DBH : DBL) + (size_t)r * 8);
    short8 a4 = *(const short8*)(DB4 + (size_t)r * 8);
    f32x16 acc = d2_tile(a1, a2, a3, a4, b1, b3, b4);
    int rb = r0 + tt * 32 + 4 * hi;
#pragma unroll
    for (int i = 0; i < 16; ++i) {
      float d2v = acc[i];
      if (d2v <= T0q) {  // rare per lane (~1.3%); exec-mask skip when none
        int slot = atomicAdd(&cnt[lo32], 1);
        if (slot < CAP) {
          listd[lo32][slot] = d2v;
          listi[lo32][slot] = rb + (i & 3) + 8 * (i >> 2);
        }
      }
    }
  }
  __syncthreads();

  // ---- stage C(i): t<32 exact top-10 -> T, den ----
  float den = 0.f;
  if (t < 32) {
    int n = min(cnt[t], CAP);
    float dd[10];
#pragma unroll
    for (int k = 0; k < 10; ++k) dd[k] = 3.4e38f;
    int j = 0;
#pragma unroll 1
    for (; j + 1 < n; j += 2) INSERT2(dd, listd[t][j], listd[t][j + 1]);
    if (j < n) INSERT2(dd, listd[t][j], 3.4e38f);
    const float C2 = -14.4269504088896340736f;
#pragma unroll
    for (int k = 0; k < 10; ++k) den += exp2f(dd[k] * C2);
    T0L[t] = dd[9];  // reuse (T0 dead): exact 10th-smallest = T
  }
  __syncthreads();

  // ---- stage C(ii): all threads, partial num with global label gather ----
  {
    const float C2 = -14.4269504088896340736f;
    int qc = t >> 4, s0 = t & 15;
    int n = min(cnt[qc], CAP);
    float Tq = T0L[qc];
    float nump = 0.f;
    for (int s = s0; s < n; s += 16) {
      float v = listd[qc][s];
      if (v <= Tq) nump = fmaf(exp2f(v * C2), labels[listi[qc][s]], nump);
    }
    pn[qc][s0] = nump;
  }
  __syncthreads();
  if (t < 32) {
    float num = 0.f;
#pragma unroll
    for (int g = 0; g < 16; ++g) num += pn[t][g];
    out[blockIdx.x * 32 + t] = num / (den + 1e-8f);
  }
}

extern "C" void kernel_launch(void* const* d_in, const int* in_sizes, int n_in,
                              void* d_out, int out_size, void* d_ws, size_t ws_size,
                              hipStream_t stream) {
  const float* bg = (const float*)d_in[0];
  const float* ed = (const float*)d_in[1];
  const float* w1 = (const float*)d_in[3];
  const float* b1 = (const float*)d_in[4];
  const float* g1 = (const float*)d_in[5];
  const float* be1 = (const float*)d_in[6];
  const float* m1 = (const float*)d_in[7];
  const float* v1 = (const float*)d_in[8];
  const float* w2 = (const float*)d_in[9];
  const float* b2 = (const float*)d_in[10];
  const float* g2 = (const float*)d_in[11];
  const float* be2 = (const float*)d_in[12];
  const float* m2 = (const float*)d_in[13];
  const float* v2 = (const float*)d_in[14];
  const float* w3 = (const float*)d_in[15];
  const float* b3 = (const float*)d_in[16];
  const float* db = (const float*)d_in[17];
  const float* labels = (const float*)d_in[18];
  float* out = (float*)d_out;

  char* ws = (char*)d_ws;
  // layout:
  //  [0,2M)     A (conv1 out; dead after conv2)
  //  [2M,6M)    B (conv2 out; live through knn prologue)
  //  [6M,6.25M) DBH/DBM/DBL/DB4 (4x64KB)
  const size_t MB = 1024 * 1024;
  float* A = (float*)(ws + 0);
  float* B = (float*)(ws + 2 * MB);
  unsigned short* DBH = (unsigned short*)(ws + 6 * MB);
  unsigned short* DBM = DBH + (size_t)MDB * 8;
  unsigned short* DBL = DBM + (size_t)MDB * 8;
  unsigned short* DB4 = DBL + (size_t)MDB * 8;

  k_conv1p<<<144, 256, 0, stream>>>(bg, ed, w1, b1, g1, be1, m1, v1, A, db,
                                    DBH, DBM, DBL, DB4);
  k_conv2<<<4 * 128, 256, 0, stream>>>(A, w2, b2, g2, be2, m2, v2, B);
  k_knn_fused<<<NVOX / 32, 512, 0, stream>>>(B, w3, b3, DBH, DBM, DBL, DB4,
                                             labels, out);
}